// Round 13
// baseline (140.785 us; speedup 1.0000x reference)
//
#include <hip/hip_runtime.h>
#include <hip/hip_fp16.h>

#define N_NODES 100000
#define N_EDGES 1600000
#define HIDDEN 64
#define RPB 512                                  // rows per bucket
#define NCB ((N_NODES + RPB - 1) / RPB)          // 196 buckets
#define CAP 8960                                 // padded bucket capacity
#define R1_THREADS 512
#define R1_BATCH 6144
#define R1_PER_T (R1_BATCH / R1_THREADS)         // 12 edges per thread
#define FINE_SLOTS 9                             // ceil(CAP / 1024)
#define NSLICE 4                                 // hidden-dim slices (16 dims, 3.2MB fp16 each)

// ---------------- P0: convert x to fp16 SLICED layout + zero ccursor ---------------
// slice s holds dims [16s,16s+16) node-major: xhs[s][node*16 ushorts]
__global__ void __launch_bounds__(256) conv_sliced_zero_kernel(
        const float4* __restrict__ x4, ushort4* __restrict__ xhs,
        int* __restrict__ ccursor) {
    if (blockIdx.x == 0 && threadIdx.x < NCB) ccursor[threadIdx.x] = 0;
    int i = blockIdx.x * blockDim.x + threadIdx.x;
    const int stride = gridDim.x * blockDim.x;
    const int n4 = N_NODES * 16;
    for (; i < n4; i += stride) {
        const float4 v = x4[i];
        const int node = i >> 4, q = i & 15;
        const int s = q >> 2, w = q & 3;
        ushort4 qq;
        qq.x = __half_as_ushort(__float2half(v.x));
        qq.y = __half_as_ushort(__float2half(v.y));
        qq.z = __half_as_ushort(__float2half(v.z));
        qq.w = __half_as_ushort(__float2half(v.w));
        xhs[(size_t)s * (N_NODES * 4) + node * 4 + w] = qq;
    }
}

// ---------------- P1: coarse scatter into padded buckets (rank-from-atomic) --------
// pack: m.x = (row&511)<<17 | col   (col < 2^17), m.y = val bits
__global__ void __launch_bounds__(R1_THREADS) coarse_scatter_pad_kernel(
        const int* __restrict__ rows, const int* __restrict__ cols,
        const float* __restrict__ vals, int* __restrict__ ccursor,
        int2* __restrict__ cbuf) {
    __shared__ int hist[NCB];
    __shared__ int base[NCB];
    const int t = threadIdx.x;
    const int b0 = blockIdx.x * R1_BATCH;
    for (int i = t; i < NCB; i += R1_THREADS) hist[i] = 0;
    __syncthreads();

    int  mb[R1_PER_T];
    int  rk[R1_PER_T];
    int2 md[R1_PER_T];
    #pragma unroll
    for (int k = 0; k < R1_PER_T; ++k) {
        const int e = b0 + k * R1_THREADS + t;  // coalesced
        mb[k] = -1;
        if (e < N_EDGES) {
            const int r = rows[e];
            mb[k] = r >> 9;
            md[k] = make_int2(((r & (RPB - 1)) << 17) | cols[e], __float_as_int(vals[e]));
            rk[k] = atomicAdd(&hist[mb[k]], 1);   // local rank, single LDS atomic
        }
    }
    __syncthreads();
    for (int i = t; i < NCB; i += R1_THREADS) {
        const int c = hist[i];
        base[i] = c ? (i * CAP + atomicAdd(&ccursor[i], c)) : 0;
    }
    __syncthreads();
    #pragma unroll
    for (int k = 0; k < R1_PER_T; ++k)
        if (mb[k] >= 0) cbuf[base[mb[k]] + rk[k]] = md[k];
}

// ---------------- P2: fine = internal 196-scan + row sort + CSR offs ---------------
__global__ void __launch_bounds__(1024) fine_bucket2_kernel(
        const int2* __restrict__ cbuf, const int* __restrict__ ccursor,
        int* __restrict__ offs, int2* __restrict__ ebuf) {
    __shared__ int csc[2][256];
    __shared__ int s[2][RPB];
    __shared__ int lbase[RPB];
    const int b = blockIdx.x;
    const int t = threadIdx.x;

    if (t < 256) csc[0][t] = (t < NCB) ? ccursor[t] : 0;
    __syncthreads();
    int sc = 0;
    for (int off = 1; off < 256; off <<= 1) {
        if (t < 256) csc[1 - sc][t] = csc[sc][t] + (t >= off ? csc[sc][t - off] : 0);
        __syncthreads();
        sc ^= 1;
    }
    const int dst0 = b ? csc[sc][b - 1] : 0;
    const int cnt  = min(ccursor[b], CAP);
    const int src0 = b * CAP;
    if (b == 0 && t == 0) offs[N_NODES] = N_EDGES;   // sentinel

    if (t < RPB) s[0][t] = 0;
    __syncthreads();

    int  rw[FINE_SLOTS];
    int  rk[FINE_SLOTS];
    int2 md[FINE_SLOTS];
    #pragma unroll
    for (int k = 0; k < FINE_SLOTS; ++k) {
        const int i = k * 1024 + t;
        rw[k] = -1;
        if (i < cnt) {
            const int2 m = cbuf[src0 + i];
            const int row = (m.x >> 17) & (RPB - 1);
            rw[k] = row;
            md[k] = make_int2(m.x & 0x1FFFF, m.y);
            rk[k] = atomicAdd(&s[0][row], 1);     // per-row rank
        }
    }
    __syncthreads();
    int src = 0;
    for (int off = 1; off < RPB; off <<= 1) {
        if (t < RPB) s[1 - src][t] = s[src][t] + (t >= off ? s[src][t - off] : 0);
        __syncthreads();
        src ^= 1;
    }
    if (t < RPB) {
        const int excl = dst0 + (t ? s[src][t - 1] : 0);
        lbase[t] = excl;
        const int row = (b << 9) + t;
        if (row < N_NODES) offs[row] = excl;      // CSR offsets
    }
    __syncthreads();
    #pragma unroll
    for (int k = 0; k < FINE_SLOTS; ++k)
        if (rw[k] >= 0) ebuf[lbase[rw[k]] + rk[k]] = md[k];
}

// ---------------- P3: XCD-sliced CSR SpMM, fp16 gather, fused ReLU -----------------
// slice = blockIdx & 3 -> XCDs {s, s+4} (round-robin dispatch): each XCD's L2 only
// caches its 3.2MB slice -> gathers L2-hit. 8 edge-groups x 8 lanes; lane = ushort2
// (2 dims). Shfls unconditional; pad lanes m=(0,0) -> v=0 no-op.
__global__ void __launch_bounds__(256) spmm_sliced_kernel(
        const ushort2* __restrict__ xh, const int2* __restrict__ ebuf,
        const int* __restrict__ offs, float2* __restrict__ out2) {
    const int bid = blockIdx.x;
    const int s = bid & 3;
    const int rb = bid >> 2;
    const int lane = threadIdx.x & 63;
    const int wave = threadIdx.x >> 6;
    const int r = rb * 4 + wave;
    if (r >= N_NODES) return;
    const int g = lane >> 3;
    const int h = lane & 7;
    const int start = offs[r];
    const int n = offs[r + 1] - start;
    const ushort2* xs = xh + (size_t)s * (N_NODES * 8);

    float ax = 0.f, ay = 0.f;
    for (int base = 0; base < n; base += 64) {
        const int take = min(64, n - base);
        int2 m = make_int2(0, 0);
        if (base + lane < n) m = ebuf[start + base + lane];  // coalesced meta load
        for (int j = 0; j < take; j += 16) {
            const int i0 = j + g, i1 = j + 8 + g;
            const int   c0 = __shfl(m.x, i0);
            const float v0 = __int_as_float(__shfl(m.y, i0));
            const int   c1 = __shfl(m.x, i1);
            const float v1 = __int_as_float(__shfl(m.y, i1));
            const ushort2 qa = xs[(size_t)(c0 & 0x1FFFF) * 8 + h];  // 2 loads in flight
            const ushort2 qb = xs[(size_t)(c1 & 0x1FFFF) * 8 + h];
            ax = fmaf(v0, __half2float(__ushort_as_half(qa.x)), ax);
            ay = fmaf(v0, __half2float(__ushort_as_half(qa.y)), ay);
            ax = fmaf(v1, __half2float(__ushort_as_half(qb.x)), ax);
            ay = fmaf(v1, __half2float(__ushort_as_half(qb.y)), ay);
        }
    }
    // fold the 8 edge-groups (lane bits 3,4,5)
    ax += __shfl_xor(ax, 8);  ay += __shfl_xor(ay, 8);
    ax += __shfl_xor(ax, 16); ay += __shfl_xor(ay, 16);
    ax += __shfl_xor(ax, 32); ay += __shfl_xor(ay, 32);
    if (lane < 8) {
        float2 o;
        o.x = fmaxf(ax, 0.f);
        o.y = fmaxf(ay, 0.f);
        out2[(size_t)r * 32 + s * 8 + h] = o;
    }
}

// ---------------- Tier-1b: fp32-gather spmm (if no room for xh) --------------------
__global__ void __launch_bounds__(256) spmm_csr_relu_f4_kernel(
        const float4* __restrict__ x4, const int2* __restrict__ ebuf,
        const int* __restrict__ offs, float4* __restrict__ out4) {
    const int lane = threadIdx.x & 63;
    const int g = lane >> 4;
    const int h = lane & 15;
    const int wave = threadIdx.x >> 6;
    const int r = blockIdx.x * 4 + wave;
    if (r >= N_NODES) return;
    const int start = offs[r];
    const int n = offs[r + 1] - start;

    float4 acc = make_float4(0.f, 0.f, 0.f, 0.f);
    for (int base = 0; base < n; base += 64) {
        const int take = min(64, n - base);
        int2 m = make_int2(0, 0);
        if (base + lane < n) m = ebuf[start + base + lane];
        for (int j = 0; j < take; j += 8) {
            const int j0 = j + g, j1 = j + 4 + g;
            const int   c0 = __shfl(m.x, j0);
            const float v0 = __int_as_float(__shfl(m.y, j0));
            const int   c1 = __shfl(m.x, j1);
            const float v1 = __int_as_float(__shfl(m.y, j1));
            const float4 a  = x4[(size_t)c0 * 16 + h];
            const float4 bq = x4[(size_t)c1 * 16 + h];
            acc.x = fmaf(v0, a.x, acc.x);  acc.y = fmaf(v0, a.y, acc.y);
            acc.z = fmaf(v0, a.z, acc.z);  acc.w = fmaf(v0, a.w, acc.w);
            acc.x = fmaf(v1, bq.x, acc.x); acc.y = fmaf(v1, bq.y, acc.y);
            acc.z = fmaf(v1, bq.z, acc.z); acc.w = fmaf(v1, bq.w, acc.w);
        }
    }
    acc.x += __shfl_xor(acc.x, 16); acc.y += __shfl_xor(acc.y, 16);
    acc.z += __shfl_xor(acc.z, 16); acc.w += __shfl_xor(acc.w, 16);
    acc.x += __shfl_xor(acc.x, 32); acc.y += __shfl_xor(acc.y, 32);
    acc.z += __shfl_xor(acc.z, 32); acc.w += __shfl_xor(acc.w, 32);
    if (lane < 16) {
        float4 o;
        o.x = fmaxf(acc.x, 0.f); o.y = fmaxf(acc.y, 0.f);
        o.z = fmaxf(acc.z, 0.f); o.w = fmaxf(acc.w, 0.f);
        out4[(size_t)r * 16 + h] = o;
    }
}

// ================= Tier-3 fallback =================
__global__ void spmm_scatter_kernel(const float* __restrict__ x,
                                    const int* __restrict__ rows,
                                    const int* __restrict__ cols,
                                    const float* __restrict__ vals,
                                    float* __restrict__ f) {
    const int lane = threadIdx.x & 63;
    const int wave = (blockIdx.x * blockDim.x + threadIdx.x) >> 6;
    const int nWaves = (gridDim.x * blockDim.x) >> 6;
    for (int e = wave; e < N_EDGES; e += nWaves)
        atomicAdd(&f[rows[e] * HIDDEN + lane], vals[e] * x[cols[e] * HIDDEN + lane]);
}
__global__ void relu_inplace_kernel(float4* __restrict__ f, int n4) {
    int i = blockIdx.x * blockDim.x + threadIdx.x;
    const int stride = gridDim.x * blockDim.x;
    for (; i < n4; i += stride) {
        float4 v = f[i];
        v.x = fmaxf(v.x, 0.0f); v.y = fmaxf(v.y, 0.0f);
        v.z = fmaxf(v.z, 0.0f); v.w = fmaxf(v.w, 0.0f);
        f[i] = v;
    }
}

extern "C" void kernel_launch(void* const* d_in, const int* in_sizes, int n_in,
                              void* d_out, int out_size, void* d_ws, size_t ws_size,
                              hipStream_t stream) {
    const float* x    = (const float*)d_in[1];
    const int*   rows = (const int*)d_in[2];
    const int*   cols = (const int*)d_in[3];
    const float* vals = (const float*)d_in[4];
    float* out = (float*)d_out;
    char* ws = (char*)d_ws;

    // ws: ccursor[NCB] | offs[N+1] | cbuf[NCB*CAP] | ebuf[E] | xh[N*H] (4 slices)
    const size_t ccursor_off = 0;
    const size_t offs_off    = ccursor_off + (size_t)NCB * 4;
    size_t cbuf_off = offs_off + (size_t)(N_NODES + 1) * 4;
    cbuf_off = (cbuf_off + 15) & ~(size_t)15;
    const size_t ebuf_off = cbuf_off + (size_t)NCB * CAP * 8;
    const size_t xh_off   = ebuf_off + (size_t)N_EDGES * 8;      // 16B-aligned
    const size_t ws_t1b = xh_off;                                // fp32 gather path
    const size_t ws_t1  = xh_off + (size_t)N_NODES * HIDDEN * 2; // + fp16 x (sliced)

    if (ws_size >= ws_t1b) {
        int*  ccursor = (int*)(ws + ccursor_off);
        int*  offs    = (int*)(ws + offs_off);
        int2* cbuf    = (int2*)(ws + cbuf_off);
        int2* ebuf    = (int2*)(ws + ebuf_off);
        const bool fp16_path = (ws_size >= ws_t1);

        if (fp16_path) {
            ushort4* xhs = (ushort4*)(ws + xh_off);
            conv_sliced_zero_kernel<<<2048, 256, 0, stream>>>(
                (const float4*)x, xhs, ccursor);
        } else {
            hipMemsetAsync(ccursor, 0, (size_t)NCB * 4, stream);
        }
        coarse_scatter_pad_kernel<<<(N_EDGES + R1_BATCH - 1) / R1_BATCH, R1_THREADS,
                                    0, stream>>>(rows, cols, vals, ccursor, cbuf);
        fine_bucket2_kernel<<<NCB, 1024, 0, stream>>>(cbuf, ccursor, offs, ebuf);
        if (fp16_path) {
            const ushort2* xh = (const ushort2*)(ws + xh_off);
            spmm_sliced_kernel<<<(N_NODES / 4) * NSLICE, 256, 0, stream>>>(
                xh, ebuf, offs, (float2*)out);
        } else {
            spmm_csr_relu_f4_kernel<<<N_NODES / 4, 256, 0, stream>>>(
                (const float4*)x, ebuf, offs, (float4*)out);
        }
        return;
    }

    // Tier-3: global-atomic scatter
    hipMemsetAsync(d_out, 0, (size_t)N_NODES * HIDDEN * sizeof(float), stream);
    spmm_scatter_kernel<<<2048, 256, 0, stream>>>(x, rows, cols, vals, out);
    relu_inplace_kernel<<<2048, 256, 0, stream>>>((float4*)d_out,
                                                  (N_NODES * HIDDEN) / 4);
}